// Round 1
// baseline (177.628 us; speedup 1.0000x reference)
//
#include <hip/hip_runtime.h>

// SKA: per-pixel dynamic depthwise 5x5 conv
// x: [B=8, C=256, H=64, W=64] f32
// w: [B=8, G=8, K2=25, H=64, W=64] f32
// out[b,c,h,w] = sum_k x[b,c,h+k/5-2,w+k%5-2] * w[b,g,k,h,w], g = c/32
//
// Design A (round 1): thread-per-pixel, block = one (b,g) x 4-row band.
// 25 weights live in VGPRs (loaded once, boundary mask folded in),
// inner loop over 32 channels: 25 clamped-offset loads + 25 FMAs.

#define B_ 8
#define C_ 256
#define G_ 8
#define CG_ 32
#define H_ 64
#define W_ 64
#define K2_ 25
#define HW_ (H_ * W_)

__global__ __launch_bounds__(256, 4) void ska_kernel(
    const float* __restrict__ x, const float* __restrict__ w,
    float* __restrict__ out) {
  const int tid = threadIdx.x;
  const int wp = tid & 63;   // pixel column == lane id -> coalesced
  const int hr = tid >> 6;   // 0..3 row within band
  const int blk = blockIdx.x;  // 0..1023
  const int hband = blk & 15;  // 16 bands of 4 rows
  const int bg = blk >> 4;     // 0..63
  const int g = bg & 7;
  const int b = bg >> 3;
  const int h = hband * 4 + hr;

  // Load the 25 per-pixel weights once; fold zero-pad mask into the weight,
  // clamp the tap offset so the (masked) load address is always in-bounds.
  float wk[K2_];
  int off[K2_];  // element offset within one channel plane [64*64]
  const float* wbase =
      w + ((size_t)(b * G_ + g) * K2_ * HW_) + (size_t)h * W_ + wp;
#pragma unroll
  for (int k = 0; k < K2_; ++k) {
    const int di = k / 5 - 2;
    const int dj = k % 5 - 2;
    const int hh = h + di;
    const int ww = wp + dj;
    const bool inb = ((unsigned)hh < (unsigned)H_) && ((unsigned)ww < (unsigned)W_);
    const float wv = wbase[(size_t)k * HW_];
    wk[k] = inb ? wv : 0.0f;
    const int hc = min(max(hh, 0), H_ - 1);
    const int wc = min(max(ww, 0), W_ - 1);
    off[k] = hc * W_ + wc;
  }

  const size_t chan0 = (size_t)(b * C_ + g * CG_) * HW_;
  const float* xb = x + chan0;
  float* ob = out + chan0 + (size_t)h * W_ + wp;

#pragma unroll 2
  for (int c = 0; c < CG_; ++c) {
    const float* xc = xb + (size_t)c * HW_;  // wave-uniform base
    float sum = 0.0f;
#pragma unroll
    for (int k = 0; k < K2_; ++k) {
      sum = fmaf(xc[off[k]], wk[k], sum);
    }
    ob[(size_t)c * HW_] = sum;
  }
}

extern "C" void kernel_launch(void* const* d_in, const int* in_sizes, int n_in,
                              void* d_out, int out_size, void* d_ws,
                              size_t ws_size, hipStream_t stream) {
  const float* x = (const float*)d_in[0];
  const float* w = (const float*)d_in[1];
  float* out = (float*)d_out;
  // grid: B*G * (H/4 bands) = 8*8*16 = 1024 blocks of 256 threads
  ska_kernel<<<dim3(1024), dim3(256), 0, stream>>>(x, w, out);
}

// Round 2
// 131.965 us; speedup vs baseline: 1.3460x; 1.3460x over previous
//
#include <hip/hip_runtime.h>

// SKA: per-pixel dynamic depthwise 5x5 conv
// x: [B=8, C=256, H=64, W=64] f32
// w: [B=8, G=8, K2=25, H=64, W=64] f32
// out[b,c,h,w] = sum_k x[b,c,h+k/5-2,w+k%5-2] * w[b,g,k,h,w], g = c/32
//
// Design B (round 2): 4 pixels per thread (float4 column quad).
// - per channel: 15 float4 x-loads (3 per tap-row x 5 rows) -> 4 outputs
//   (vs 25 scalar loads -> 1 output in round 1): ~6x fewer VMEM instrs.
// - 25 float4 per-pixel weights held in VGPRs across 16 channels,
//   boundary masks folded into the weights (branch-free, clamped addrs).
// - __launch_bounds__(256,2): VGPR cap 256 so weight array doesn't spill
//   (round 1's cap of 128 + 48 reported VGPRs suggests scratch spill).

#define B_ 8
#define C_ 256
#define G_ 8
#define CG_ 32
#define H_ 64
#define W_ 64
#define K2_ 25
#define HW_ (H_ * W_)
#define NCH 16   // channels per block (CG_/2)
#define ROWS 16  // output rows per block band

__global__ __launch_bounds__(256, 2) void ska_kernel(
    const float* __restrict__ x, const float* __restrict__ w,
    float* __restrict__ out) {
  const int tid = threadIdx.x;
  const int j = tid & 15;   // column quad index: cols 4j..4j+3
  const int r = tid >> 4;   // row within band
  const int blk = blockIdx.x;  // 512 blocks
  const int chhalf = blk & 1;
  const int band = (blk >> 1) & 3;
  const int g = (blk >> 3) & 7;
  const int b = blk >> 6;
  const int h = band * ROWS + r;
  const int wcol = j * 4;

  // ---- load 25 per-pixel weight quads once; fold OOB masks in ----
  float wk[K2_][4];
  const float* wb =
      w + (size_t)(b * G_ + g) * K2_ * HW_ + (size_t)h * W_ + wcol;
#pragma unroll
  for (int k = 0; k < K2_; ++k) {
    const int di = k / 5 - 2;
    const int dj = k % 5 - 2;
    const int hh = h + di;
    const bool rowok = (unsigned)hh < (unsigned)H_;
    const float4 wv = *(const float4*)(wb + (size_t)k * HW_);
#pragma unroll
    for (int t = 0; t < 4; ++t) {
      const int cc = wcol + t + dj;
      const bool ok = rowok && ((unsigned)cc < (unsigned)W_);
      wk[k][t] = ok ? ((const float*)&wv)[t] : 0.0f;
    }
  }

  // ---- clamped row offsets and column bases for the 3 f4 loads ----
  int rowoff[5];
#pragma unroll
  for (int di = 0; di < 5; ++di) {
    int hh = h + di - 2;
    hh = min(max(hh, 0), H_ - 1);
    rowoff[di] = hh * W_;
  }
  const int c0m = max(wcol - 4, 0);       // covers cols wcol-4..wcol-1 (garbage ok at j=0)
  const int c2m = min(wcol + 4, W_ - 4);  // covers cols wcol+4..wcol+7 (garbage ok at j=15)

  const size_t chan0 = (size_t)(b * C_ + g * CG_ + chhalf * NCH) * HW_;
  const float* xc = x + chan0;
  float* ob = out + chan0 + (size_t)h * W_ + wcol;

  for (int c = 0; c < NCH; ++c) {
    const float* xp = xc + (size_t)c * HW_;
    alignas(16) float acc[4] = {0.f, 0.f, 0.f, 0.f};
#pragma unroll
    for (int di = 0; di < 5; ++di) {
      alignas(16) float xr[12];
      const float* rp = xp + rowoff[di];
      *(float4*)&xr[0] = *(const float4*)(rp + c0m);
      *(float4*)&xr[4] = *(const float4*)(rp + wcol);
      *(float4*)&xr[8] = *(const float4*)(rp + c2m);
      // xr[idx] holds col (wcol-4+idx) for interior lanes; valid taps use
      // idx = 2+t+dj in [2,9]; boundary-lane garbage idx only meets wk==0.
#pragma unroll
      for (int dj = 0; dj < 5; ++dj) {
        const int k = di * 5 + dj;
#pragma unroll
        for (int t = 0; t < 4; ++t) {
          acc[t] = fmaf(xr[2 + t + dj], wk[k][t], acc[t]);
        }
      }
    }
    *(float4*)(ob + (size_t)c * HW_) = *(const float4*)acc;
  }
}

extern "C" void kernel_launch(void* const* d_in, const int* in_sizes, int n_in,
                              void* d_out, int out_size, void* d_ws,
                              size_t ws_size, hipStream_t stream) {
  const float* x = (const float*)d_in[0];
  const float* w = (const float*)d_in[1];
  float* out = (float*)d_out;
  // grid: B*G * 4 bands * 2 channel-halves = 512 blocks of 256 threads
  ska_kernel<<<dim3(512), dim3(256), 0, stream>>>(x, w, out);
}